// Round 1
// baseline (280.614 us; speedup 1.0000x reference)
//
#include <hip/hip_runtime.h>
#include <hip/hip_bf16.h>

typedef unsigned short u16;
typedef unsigned int u32;
typedef __attribute__((ext_vector_type(8))) short bf16x8;
typedef __attribute__((ext_vector_type(4))) float f32x4;

#define T_DIM 2048
#define B_DIM 32
#define H_DIM 512
#define M_DIM (T_DIM * B_DIM)

__device__ inline unsigned pack2(float a, float b) {
  union { __hip_bfloat162 h2; unsigned u; } c;
  c.h2 = __float22bfloat162_rn(make_float2(a, b));
  return c.u;
}

// Direct HBM->LDS staging, no VGPR round-trip. Size must be literal 16.
// LDS dest is wave-uniform base + lane*16; global source is per-lane.
__device__ __forceinline__ void gld16(const void* g, void* s) {
  __builtin_amdgcn_global_load_lds(
      (const __attribute__((address_space(1))) void*)g,
      (__attribute__((address_space(3))) void*)s, 16, 0, 0);
}

// Precompute: r[b*512+h] = hidden[b]·W1[h] + b_attn[h]; u[h] = W3[h]·W_cov;
// W2bf = bf16(W2) in FRAGMENT-MAJOR layout: chunk (f= h>>4, ks= k>>5) of 1KB,
// within chunk: lane (quad= (k>>3)&3, c= h&15) * 16B + (k&7)*2B.
// A wave's MFMA B-fragment load == one contiguous 1KB chunk at base+lane*16.
__global__ __launch_bounds__(256) void prep_kernel(
    const float* __restrict__ hidden, const float* __restrict__ W_attn,
    const float* __restrict__ b_attn, const float* __restrict__ W_cov,
    u16* __restrict__ W2bf, float* __restrict__ r, float* __restrict__ u)
{
  const int tid = blockIdx.x * 256 + threadIdx.x;  // 0..65535
  const int pair = tid >> 2;                       // b*512 + h
  const int kq = tid & 3;
  const int b = pair >> 9, h = pair & 511;

  {
    const float* hid = hidden + b * 512 + kq * 128;
    const float* w1 = W_attn + (size_t)h * 1536 + kq * 128;
    float acc = 0.f;
    #pragma unroll 8
    for (int k = 0; k < 128; k += 4) {
      float4 x = *(const float4*)(hid + k);
      float4 w = *(const float4*)(w1 + k);
      acc += x.x * w.x + x.y * w.y + x.z * w.z + x.w * w.w;
    }
    acc += __shfl_xor(acc, 1);
    acc += __shfl_xor(acc, 2);
    if (kq == 0) r[pair] = acc + b_attn[h];
  }

  {
    int j0 = tid * 4;
    int hh = j0 >> 9, kk = j0 & 511;
    float4 w = *(const float4*)(W_attn + (size_t)hh * 1536 + 512 + kk);
    uint2 p;
    p.x = pack2(w.x, w.y);
    p.y = pack2(w.z, w.w);
    int f = hh >> 4, c = hh & 15;
    int ks = kk >> 5, quad = (kk >> 3) & 3, e = kk & 7;   // e in {0,4}
    *(uint2*)(W2bf + (size_t)((f * 16 + ks) * 64 + quad * 16 + c) * 8 + e) = p;
  }

  if (tid < 2048) {
    int h3 = tid >> 2;
    const float* w3 = W_attn + (size_t)h3 * 1536 + 1024 + kq * 128;
    const float* wc = W_cov + kq * 128;
    float su = 0.f;
    #pragma unroll 8
    for (int k = 0; k < 128; k += 4) {
      float4 a = *(const float4*)(w3 + k);
      float4 c = *(const float4*)(wc + k);
      su += a.x * c.x + a.y * c.y + a.z * c.z + a.w * c.w;
    }
    su += __shfl_xor(su, 1);
    su += __shfl_xor(su, 2);
    if (kq == 0) u[h3] = su;
  }
}

// One block (512 thr, 8 waves) per 32-row m-tile == ONE t, all 32 batches.
// Staging: 8 x global_load_lds dwordx4 per wave (1KB each, zero VGPRs, 64KB/block
// in flight -> HBM-saturating). LDS holds fp32, lane-LINEAR dest; bank-conflict
// swizzle applied on the SOURCE address (rule 21): LDS[r][G] = enc[m0+r][G^(r&7)]
// on 16B granules. K-loop is barrier-free: fp32 A read with the same XOR on the
// granule index, cvt->bf16 in VALU (idle pipe), B frags are coalesced 1KB loads
// from fragment-major W2bf (L2-resident), register double-buffered.
__global__ __launch_bounds__(512, 4) void gemm_score(
    const float* __restrict__ enc, const u16* __restrict__ W2bf,
    const float* __restrict__ r, const float* __restrict__ u,
    const float* __restrict__ vv, const float* __restrict__ cov,
    float* __restrict__ part)
{
  const int t = blockIdx.x;            // rows m = t*32 + b, b = 0..31
  const int m0 = t * 32;
  const int tid = threadIdx.x;
  const int lane = tid & 63;
  const int w = tid >> 6;              // wave id 0..7 -> n-slab [w*64, w*64+64)
  const int quad = lane >> 4, col = lane & 15;

  __shared__ float As[32 * 512];       // 64 KB fp32, [row][k], 16B-granule XOR swizzle

  // ---- Stage: wave w covers rows 4w..4w+3 (2 instrs/row). ----
  #pragma unroll
  for (int q = 0; q < 8; ++q) {
    int n = w * 8 + q;                         // LDS KB index 0..63
    int rr = n >> 1, hh = n & 1;               // row, half-row
    int gsrc = hh * 64 + (lane ^ (rr & 7));    // swizzled source granule 0..127
    gld16(enc + (size_t)(m0 + rr) * 512 + gsrc * 4, (void*)(As + n * 256));
  }
  __syncthreads();   // compiler emits vmcnt(0) before s_barrier -> staging complete

  // ---- K-loop, no barriers. B frags: coalesced 1KB loads, double-buffered. ----
  f32x4 acc[2][4] = {};
  const u16* bbase = W2bf + (size_t)w * 32768 + lane * 8;  // f-base = w*4

  bf16x8 bcur[4], bnxt[4];
  #pragma unroll
  for (int j = 0; j < 4; ++j)
    bcur[j] = *(const bf16x8*)(bbase + j * 8192);

  // Swizzled read offsets: logical granule ks*8 + quad*2 + p -> XOR low3 with
  // row&7 == col&7 (row = i*16+col, 16 = 0 mod 8) -> per-lane constants.
  const int o0 = (((quad * 2)    ) ^ (col & 7)) * 4;   // float offset within row
  const int o1 = (((quad * 2) + 1) ^ (col & 7)) * 4;
  const float* arow0 = As + col * 512;                 // i=0 row base; i=1 adds 8192

  #pragma unroll
  for (int ks = 0; ks < 16; ++ks) {
    if (ks < 15) {
      #pragma unroll
      for (int j = 0; j < 4; ++j)
        bnxt[j] = *(const bf16x8*)(bbase + j * 8192 + (ks + 1) * 512);
    }
    #pragma unroll
    for (int i = 0; i < 2; ++i) {
      const float* ap = arow0 + i * 8192 + ks * 32;
      float4 f0 = *(const float4*)(ap + o0);
      float4 f1 = *(const float4*)(ap + o1);
      union { bf16x8 v; u32 uu[4]; } af;
      af.uu[0] = pack2(f0.x, f0.y);
      af.uu[1] = pack2(f0.z, f0.w);
      af.uu[2] = pack2(f1.x, f1.y);
      af.uu[3] = pack2(f1.z, f1.w);
      #pragma unroll
      for (int j = 0; j < 4; ++j)
        acc[i][j] = __builtin_amdgcn_mfma_f32_16x16x32_bf16(af.v, bcur[j], acc[i][j], 0, 0, 0);
    }
    #pragma unroll
    for (int j = 0; j < 4; ++j) bcur[j] = bnxt[j];
  }

  // ---- Epilogue: e = relu(acc + r[b,h] + cov[b,t]*u[h]); partial = e·v over wave's 64 h ----
  float uj[4], vj[4];
  #pragma unroll
  for (int j = 0; j < 4; ++j) {
    int gh = w * 64 + j * 16 + col;
    uj[j] = u[gh];
    vj[j] = vv[gh];
  }
  #pragma unroll
  for (int i = 0; i < 2; ++i) {
    #pragma unroll
    for (int reg = 0; reg < 4; ++reg) {
      int b = i * 16 + quad * 4 + reg;      // C/D layout: row = quad*4 + reg
      float cv = cov[b * 2048 + t];
      float s = 0.f;
      #pragma unroll
      for (int j = 0; j < 4; ++j) {
        float rv = r[b * 512 + w * 64 + j * 16 + col];
        float e = acc[i][j][reg] + rv + cv * uj[j];
        e = fmaxf(e, 0.f);
        s += e * vj[j];
      }
      s += __shfl_xor(s, 1);
      s += __shfl_xor(s, 2);
      s += __shfl_xor(s, 4);
      s += __shfl_xor(s, 8);
      if (col == 0) part[(size_t)(w * 32 + b) * 2048 + t] = s;
    }
  }
}

// Softmax over T per batch + coverage update. 32 blocks x 256 threads. part layout [p][b][t].
__global__ __launch_bounds__(256) void softmax_kernel(
    const float* __restrict__ part, const float* __restrict__ cov, float* __restrict__ out)
{
  const int b = blockIdx.x;
  const int tid = threadIdx.x;
  const int lane = tid & 63, wid = tid >> 6;
  __shared__ float red[4];
  float loc[8];
  float lmax = -3.4e38f;
  #pragma unroll
  for (int i = 0; i < 8; ++i) {
    int t = tid + i * 256;
    float s = 0.f;
    #pragma unroll
    for (int p = 0; p < 8; ++p) s += part[(size_t)(p * 32 + b) * 2048 + t];
    loc[i] = s;
    lmax = fmaxf(lmax, s);
  }
  #pragma unroll
  for (int o = 32; o; o >>= 1) lmax = fmaxf(lmax, __shfl_xor(lmax, o));
  if (lane == 0) red[wid] = lmax;
  __syncthreads();
  float bmax = fmaxf(fmaxf(red[0], red[1]), fmaxf(red[2], red[3]));
  __syncthreads();
  float lsum = 0.f;
  #pragma unroll
  for (int i = 0; i < 8; ++i) { loc[i] = __expf(loc[i] - bmax); lsum += loc[i]; }
  #pragma unroll
  for (int o = 32; o; o >>= 1) lsum += __shfl_xor(lsum, o);
  if (lane == 0) red[wid] = lsum;
  __syncthreads();
  float inv = 1.0f / (red[0] + red[1] + red[2] + red[3]);
  #pragma unroll
  for (int i = 0; i < 8; ++i) {
    int t = tid + i * 256;
    float a = loc[i] * inv;
    out[b * 2048 + t] = a;                               // attn_weights [B,1,T]
    out[65536 + b * 2048 + t] = cov[b * 2048 + t] + a;   // coverage_new [B,T]
  }
}

extern "C" void kernel_launch(void* const* d_in, const int* in_sizes, int n_in,
                              void* d_out, int out_size, void* d_ws, size_t ws_size,
                              hipStream_t stream) {
  const float* hidden = (const float*)d_in[0];   // [1,B,H]
  const float* enc    = (const float*)d_in[1];   // [T,B,H]
  const float* cov    = (const float*)d_in[2];   // [B,T]
  const float* W_attn = (const float*)d_in[3];   // [H,3H]
  const float* b_attn = (const float*)d_in[4];   // [H]
  const float* vv     = (const float*)d_in[5];   // [H]
  const float* W_cov  = (const float*)d_in[6];   // [H,1]
  float* out = (float*)d_out;

  u16* W2bf = (u16*)d_ws;                              // 512 KB (fragment-major)
  float* r  = (float*)((char*)d_ws + 512 * 1024);      // 64 KB
  float* u  = r + 32 * 512;                            // 2 KB
  float* part = u + 512;                               // 8 * 65536 * 4 = 2 MB

  hipLaunchKernelGGL(prep_kernel, dim3(256), dim3(256), 0, stream,
                     hidden, W_attn, b_attn, W_cov, W2bf, r, u);
  hipLaunchKernelGGL(gemm_score, dim3(2048), dim3(512), 0, stream,
                     enc, W2bf, r, u, vv, cov, part);
  hipLaunchKernelGGL(softmax_kernel, dim3(32), dim3(256), 0, stream,
                     part, cov, out);
}

// Round 2
// 267.400 us; speedup vs baseline: 1.0494x; 1.0494x over previous
//
#include <hip/hip_runtime.h>
#include <hip/hip_bf16.h>

typedef unsigned short u16;
typedef unsigned int u32;
typedef __attribute__((ext_vector_type(8))) short bf16x8;
typedef __attribute__((ext_vector_type(4))) float f32x4;

#define T_DIM 2048
#define B_DIM 32
#define H_DIM 512
#define M_DIM (T_DIM * B_DIM)

__device__ inline unsigned pack2(float a, float b) {
  union { __hip_bfloat162 h2; unsigned u; } c;
  c.h2 = __float22bfloat162_rn(make_float2(a, b));
  return c.u;
}

// Direct HBM->LDS staging, no VGPR round-trip. Size must be literal 16.
__device__ __forceinline__ void gld16(const void* g, void* s) {
  __builtin_amdgcn_global_load_lds(
      (const __attribute__((address_space(1))) void*)g,
      (__attribute__((address_space(3))) void*)s, 16, 0, 0);
}

// Precompute: r[b*512+h] = hidden[b]·W1[h] + b_attn[h]; u[h] = W3[h]·W_cov;
// W2bf = bf16(W2) in FRAGMENT-MAJOR layout (unchanged, harness-verified).
__global__ __launch_bounds__(256) void prep_kernel(
    const float* __restrict__ hidden, const float* __restrict__ W_attn,
    const float* __restrict__ b_attn, const float* __restrict__ W_cov,
    u16* __restrict__ W2bf, float* __restrict__ r, float* __restrict__ u)
{
  const int tid = blockIdx.x * 256 + threadIdx.x;  // 0..65535
  const int pair = tid >> 2;                       // b*512 + h
  const int kq = tid & 3;
  const int b = pair >> 9, h = pair & 511;

  {
    const float* hid = hidden + b * 512 + kq * 128;
    const float* w1 = W_attn + (size_t)h * 1536 + kq * 128;
    float acc = 0.f;
    #pragma unroll 8
    for (int k = 0; k < 128; k += 4) {
      float4 x = *(const float4*)(hid + k);
      float4 w = *(const float4*)(w1 + k);
      acc += x.x * w.x + x.y * w.y + x.z * w.z + x.w * w.w;
    }
    acc += __shfl_xor(acc, 1);
    acc += __shfl_xor(acc, 2);
    if (kq == 0) r[pair] = acc + b_attn[h];
  }

  {
    int j0 = tid * 4;
    int hh = j0 >> 9, kk = j0 & 511;
    float4 w = *(const float4*)(W_attn + (size_t)hh * 1536 + 512 + kk);
    uint2 p;
    p.x = pack2(w.x, w.y);
    p.y = pack2(w.z, w.w);
    int f = hh >> 4, c = hh & 15;
    int ks = kk >> 5, quad = (kk >> 3) & 3, e = kk & 7;   // e in {0,4}
    *(uint2*)(W2bf + (size_t)((f * 16 + ks) * 64 + quad * 16 + c) * 8 + e) = p;
  }

  if (tid < 2048) {
    int h3 = tid >> 2;
    const float* w3 = W_attn + (size_t)h3 * 1536 + 1024 + kq * 128;
    const float* wc = W_cov + kq * 128;
    float su = 0.f;
    #pragma unroll 8
    for (int k = 0; k < 128; k += 4) {
      float4 a = *(const float4*)(w3 + k);
      float4 c = *(const float4*)(wc + k);
      su += a.x * c.x + a.y * c.y + a.z * c.z + a.w * c.w;
    }
    su += __shfl_xor(su, 1);
    su += __shfl_xor(su, 2);
    if (kq == 0) u[h3] = su;
  }
}

// One block (512 thr, 8 waves) per t (32 rows, all batches).
// v3: latency-hiding K-loop — B frags register double-buffered 2 iterations
// deep (covers ~200cy L2 latency), A frags ds_read one iteration ahead
// (covers ~120cy LDS latency). Epilogue reduces the 8 waves' partials via
// LDS (reusing As) so part holds FINAL scores [b][t] (8x less write traffic,
// no 8-way gather in softmax). Chunked XCD swizzle on t for part-line sharing.
__global__ __launch_bounds__(512, 4) void gemm_score(
    const float* __restrict__ enc, const u16* __restrict__ W2bf,
    const float* __restrict__ r, const float* __restrict__ u,
    const float* __restrict__ vv, const float* __restrict__ cov,
    float* __restrict__ part)
{
  const int bid = blockIdx.x;
  const int t = (bid & 7) * 256 + (bid >> 3);   // 2048 % 8 == 0 -> bijective
  const int m0 = t * 32;
  const int tid = threadIdx.x;
  const int lane = tid & 63;
  const int w = tid >> 6;              // wave id 0..7 -> n-slab [w*64, w*64+64)
  const int quad = lane >> 4, col = lane & 15;

  __shared__ float As[32 * 512];       // 64 KB fp32, [row][k], 16B-granule XOR swizzle

  // ---- Stage: zero-VGPR HBM->LDS, source-side swizzle (verified in r1). ----
  #pragma unroll
  for (int q = 0; q < 8; ++q) {
    int n = w * 8 + q;                         // LDS KB index 0..63
    int rr = n >> 1, hh = n & 1;               // row, half-row
    int gsrc = hh * 64 + (lane ^ (rr & 7));    // swizzled source granule 0..127
    gld16(enc + (size_t)(m0 + rr) * 512 + gsrc * 4, (void*)(As + n * 256));
  }
  __syncthreads();

  // ---- K-loop, no barriers. ----
  f32x4 acc[2][4] = {};
  const u16* bbase = W2bf + (size_t)w * 32768 + lane * 8;  // f-base = w*4

  bf16x8 bb[2][4];
  #pragma unroll
  for (int j = 0; j < 4; ++j) {
    bb[0][j] = *(const bf16x8*)(bbase + j * 8192);
    bb[1][j] = *(const bf16x8*)(bbase + j * 8192 + 512);
  }

  const int o0 = (((quad * 2)    ) ^ (col & 7)) * 4;   // swizzled float offsets
  const int o1 = (((quad * 2) + 1) ^ (col & 7)) * 4;
  const float* arow0 = As + col * 512;                 // i=0 row base; i=1 adds 8192

  float4 areg[2][2][2];
  #pragma unroll
  for (int i = 0; i < 2; ++i) {
    const float* ap = arow0 + i * 8192;
    areg[0][i][0] = *(const float4*)(ap + o0);
    areg[0][i][1] = *(const float4*)(ap + o1);
  }

  #pragma unroll
  for (int ks = 0; ks < 16; ++ks) {
    // A prefetch for ks+1: ds_read latency hides under this iteration's MFMAs
    if (ks < 15) {
      #pragma unroll
      for (int i = 0; i < 2; ++i) {
        const float* ap = arow0 + i * 8192 + (ks + 1) * 32;
        areg[(ks + 1) & 1][i][0] = *(const float4*)(ap + o0);
        areg[(ks + 1) & 1][i][1] = *(const float4*)(ap + o1);
      }
    }
    #pragma unroll
    for (int i = 0; i < 2; ++i) {
      float4 f0 = areg[ks & 1][i][0];
      float4 f1 = areg[ks & 1][i][1];
      union { bf16x8 v; u32 uu[4]; } af;
      af.uu[0] = pack2(f0.x, f0.y);
      af.uu[1] = pack2(f0.z, f0.w);
      af.uu[2] = pack2(f1.x, f1.y);
      af.uu[3] = pack2(f1.z, f1.w);
      #pragma unroll
      for (int j = 0; j < 4; ++j)
        acc[i][j] = __builtin_amdgcn_mfma_f32_16x16x32_bf16(af.v, bb[ks & 1][j], acc[i][j], 0, 0, 0);
    }
    // B prefetch for ks+2: issued after its buffer's last consumer -> in flight
    // for a full iteration (covers L2 latency)
    if (ks < 14) {
      #pragma unroll
      for (int j = 0; j < 4; ++j)
        bb[ks & 1][j] = *(const bf16x8*)(bbase + j * 8192 + (ks + 2) * 512);
    }
  }

  // ---- Epilogue: e = relu(acc + r[b,h] + cov[b,t]*u[h]); s = e·v over wave's 64 h;
  //      then reduce s across the 8 waves via LDS (As is dead) -> final score. ----
  float uj[4], vj[4];
  #pragma unroll
  for (int j = 0; j < 4; ++j) {
    int gh = w * 64 + j * 16 + col;
    uj[j] = u[gh];
    vj[j] = vv[gh];
  }

  __syncthreads();                 // all waves done reading As; safe to reuse
  float* red = As;                 // red[w*32 + b]

  #pragma unroll
  for (int i = 0; i < 2; ++i) {
    #pragma unroll
    for (int reg = 0; reg < 4; ++reg) {
      int b = i * 16 + quad * 4 + reg;      // C/D layout: row = quad*4 + reg
      float cv = cov[b * 2048 + t];
      float s = 0.f;
      #pragma unroll
      for (int j = 0; j < 4; ++j) {
        float rv = r[b * 512 + w * 64 + j * 16 + col];
        float e = acc[i][j][reg] + rv + cv * uj[j];
        e = fmaxf(e, 0.f);
        s += e * vj[j];
      }
      s += __shfl_xor(s, 1);
      s += __shfl_xor(s, 2);
      s += __shfl_xor(s, 4);
      s += __shfl_xor(s, 8);
      if (col == 0) red[w * 32 + b] = s;
    }
  }
  __syncthreads();
  if (tid < 32) {
    float s = 0.f;
    #pragma unroll
    for (int p = 0; p < 8; ++p) s += red[p * 32 + tid];
    part[(size_t)tid * 2048 + t] = s;       // final score[b][t]
  }
}

// Softmax over T per batch + coverage update. 32 blocks x 256 threads.
// part now holds final scores [b][t] -> single coalesced read.
__global__ __launch_bounds__(256) void softmax_kernel(
    const float* __restrict__ part, const float* __restrict__ cov, float* __restrict__ out)
{
  const int b = blockIdx.x;
  const int tid = threadIdx.x;
  const int lane = tid & 63, wid = tid >> 6;
  __shared__ float red[4];
  float loc[8];
  float lmax = -3.4e38f;
  #pragma unroll
  for (int i = 0; i < 8; ++i) {
    int t = tid + i * 256;
    float s = part[(size_t)b * 2048 + t];
    loc[i] = s;
    lmax = fmaxf(lmax, s);
  }
  #pragma unroll
  for (int o = 32; o; o >>= 1) lmax = fmaxf(lmax, __shfl_xor(lmax, o));
  if (lane == 0) red[wid] = lmax;
  __syncthreads();
  float bmax = fmaxf(fmaxf(red[0], red[1]), fmaxf(red[2], red[3]));
  __syncthreads();
  float lsum = 0.f;
  #pragma unroll
  for (int i = 0; i < 8; ++i) { loc[i] = __expf(loc[i] - bmax); lsum += loc[i]; }
  #pragma unroll
  for (int o = 32; o; o >>= 1) lsum += __shfl_xor(lsum, o);
  if (lane == 0) red[wid] = lsum;
  __syncthreads();
  float inv = 1.0f / (red[0] + red[1] + red[2] + red[3]);
  #pragma unroll
  for (int i = 0; i < 8; ++i) {
    int t = tid + i * 256;
    float a = loc[i] * inv;
    out[b * 2048 + t] = a;                               // attn_weights [B,1,T]
    out[65536 + b * 2048 + t] = cov[b * 2048 + t] + a;   // coverage_new [B,T]
  }
}

extern "C" void kernel_launch(void* const* d_in, const int* in_sizes, int n_in,
                              void* d_out, int out_size, void* d_ws, size_t ws_size,
                              hipStream_t stream) {
  const float* hidden = (const float*)d_in[0];   // [1,B,H]
  const float* enc    = (const float*)d_in[1];   // [T,B,H]
  const float* cov    = (const float*)d_in[2];   // [B,T]
  const float* W_attn = (const float*)d_in[3];   // [H,3H]
  const float* b_attn = (const float*)d_in[4];   // [H]
  const float* vv     = (const float*)d_in[5];   // [H]
  const float* W_cov  = (const float*)d_in[6];   // [H,1]
  float* out = (float*)d_out;

  u16* W2bf = (u16*)d_ws;                              // 512 KB (fragment-major)
  float* r  = (float*)((char*)d_ws + 512 * 1024);      // 64 KB
  float* u  = r + 32 * 512;                            // 2 KB
  float* part = u + 512;                               // 32*2048*4 = 256 KB (final scores)

  hipLaunchKernelGGL(prep_kernel, dim3(256), dim3(256), 0, stream,
                     hidden, W_attn, b_attn, W_cov, W2bf, r, u);
  hipLaunchKernelGGL(gemm_score, dim3(2048), dim3(512), 0, stream,
                     enc, W2bf, r, u, vv, cov, part);
  hipLaunchKernelGGL(softmax_kernel, dim3(32), dim3(256), 0, stream,
                     part, cov, out);
}